// Round 1
// baseline (598.504 us; speedup 1.0000x reference)
//
#include <hip/hip_runtime.h>

#define NN 50000
#define NE 800000
#define C 128

// ---------------- preprocessing: build CSR (dst -> list of src) ----------------

__global__ void count_kernel(const int* __restrict__ dst, int* __restrict__ deg, int n_edges) {
    int e = blockIdx.x * blockDim.x + threadIdx.x;
    if (e < n_edges) atomicAdd(&deg[dst[e]], 1);
}

// single-block exclusive scan of deg -> row_ptr, plus inv_deg = 1/max(deg,1)
__global__ void scan_kernel(const int* __restrict__ deg, int* __restrict__ row_ptr,
                            float* __restrict__ inv_deg, int n) {
    __shared__ int wsum[4];
    __shared__ int wpre[4];
    __shared__ int carry_s;
    int t = threadIdx.x, lane = t & 63, w = t >> 6;
    if (t == 0) carry_s = 0;
    __syncthreads();
    for (int base = 0; base < n; base += 256) {
        int i = base + t;
        int v = (i < n) ? deg[i] : 0;
        int s = v;
        #pragma unroll
        for (int off = 1; off < 64; off <<= 1) {
            int y = __shfl_up(s, off, 64);
            if (lane >= off) s += y;
        }
        if (lane == 63) wsum[w] = s;
        __syncthreads();
        int carry = carry_s;
        __syncthreads();
        if (t == 0) {
            int acc = 0;
            #pragma unroll
            for (int j = 0; j < 4; ++j) { wpre[j] = acc; acc += wsum[j]; }
            carry_s = carry + acc;
        }
        __syncthreads();
        if (i < n) {
            row_ptr[i] = carry + wpre[w] + (s - v);          // exclusive
            inv_deg[i] = 1.0f / (float)max(v, 1);
        }
        __syncthreads();
    }
    if (t == 0) row_ptr[n] = carry_s;
}

__global__ void fill_kernel(const int* __restrict__ src, const int* __restrict__ dst,
                            const int* __restrict__ row_ptr, int* __restrict__ fill,
                            int* __restrict__ col, int n_edges) {
    int e = blockIdx.x * blockDim.x + threadIdx.x;
    if (e < n_edges) {
        int d = dst[e];
        int p = atomicAdd(&fill[d], 1);
        col[row_ptr[d] + p] = src[e];
    }
}

// ---------------- mean aggregation: one wave per node ----------------

__global__ __launch_bounds__(256)
void agg_kernel(const float* __restrict__ x, const int* __restrict__ row_ptr,
                const int* __restrict__ col, const float* __restrict__ inv_deg,
                float* __restrict__ agg, int nodes) {
    int wave = (blockIdx.x * blockDim.x + threadIdx.x) >> 6;
    int lane = threadIdx.x & 63;
    if (wave >= nodes) return;
    int start = row_ptr[wave], end = row_ptr[wave + 1];
    int off = lane * 2;
    float ax = 0.f, ay = 0.f;
    int e = start;
    for (; e + 1 < end; e += 2) {
        int s0 = col[e], s1 = col[e + 1];
        float2 v0 = *(const float2*)(x + s0 * C + off);
        float2 v1 = *(const float2*)(x + s1 * C + off);
        ax += v0.x + v1.x;
        ay += v0.y + v1.y;
    }
    if (e < end) {
        int s0 = col[e];
        float2 v0 = *(const float2*)(x + s0 * C + off);
        ax += v0.x;
        ay += v0.y;
    }
    float inv = inv_deg[wave];
    *(float2*)(agg + wave * C + off) = make_float2(ax * inv, ay * inv);
}

// ---------------- fused dual GEMM + bias + PReLU ----------------
// out[r][c] = prelu( dot(Ain[r], Wl[c]) + bl[c] + dot(Xin[r], Wr[c]), slope[c] )
// block = 256 threads, tile = 64 rows x 128 cols; thread tile = 4 rows x 8 cols.

__global__ __launch_bounds__(256, 2)
void gemm_kernel(const float* __restrict__ Ain, const float* __restrict__ Xin,
                 const float* __restrict__ Wl, const float* __restrict__ bl,
                 const float* __restrict__ Wr, const float* __restrict__ slope,
                 float* __restrict__ out, int rows) {
    __shared__ float WT[C * C]; // [k][c], 64 KB
    int t = threadIdx.x;
    int tx = t & 15;            // c0 = tx*8
    int ty = t >> 4;            // rows r = row0..row0+3
    int row0 = blockIdx.x * 64 + ty * 4;

    float acc[4][8];
    #pragma unroll
    for (int r = 0; r < 4; ++r)
        #pragma unroll
        for (int j = 0; j < 8; ++j) acc[r][j] = 0.f;

    #pragma unroll
    for (int mat = 0; mat < 2; ++mat) {
        const float* W = mat ? Wr : Wl;
        const float* A = mat ? Xin : Ain;
        __syncthreads();
        // stage W^T into LDS: consecutive threads -> consecutive c (conflict-free writes)
        #pragma unroll
        for (int j = 0; j < 16; ++j) {
            int i = t + j * 256;         // 0..4095 over (c, k4)
            int c = i & 127;
            int k4 = i >> 7;             // 0..31
            float4 wv = ((const float4*)W)[c * 32 + k4];
            int k = k4 * 4;
            WT[(k + 0) * C + c] = wv.x;
            WT[(k + 1) * C + c] = wv.y;
            WT[(k + 2) * C + c] = wv.z;
            WT[(k + 3) * C + c] = wv.w;
        }
        __syncthreads();

        const float* Ar0 = A + min(row0 + 0, rows - 1) * C;
        const float* Ar1 = A + min(row0 + 1, rows - 1) * C;
        const float* Ar2 = A + min(row0 + 2, rows - 1) * C;
        const float* Ar3 = A + min(row0 + 3, rows - 1) * C;

        for (int k = 0; k < C; k += 4) {
            float4 av[4];
            av[0] = *(const float4*)(Ar0 + k);
            av[1] = *(const float4*)(Ar1 + k);
            av[2] = *(const float4*)(Ar2 + k);
            av[3] = *(const float4*)(Ar3 + k);
            #pragma unroll
            for (int kk = 0; kk < 4; ++kk) {
                float4 w0 = *(const float4*)&WT[(k + kk) * C + tx * 8];
                float4 w1 = *(const float4*)&WT[(k + kk) * C + tx * 8 + 4];
                #pragma unroll
                for (int r = 0; r < 4; ++r) {
                    float a = (kk == 0) ? av[r].x : (kk == 1) ? av[r].y
                            : (kk == 2) ? av[r].z : av[r].w;
                    acc[r][0] += a * w0.x;
                    acc[r][1] += a * w0.y;
                    acc[r][2] += a * w0.z;
                    acc[r][3] += a * w0.w;
                    acc[r][4] += a * w1.x;
                    acc[r][5] += a * w1.y;
                    acc[r][6] += a * w1.z;
                    acc[r][7] += a * w1.w;
                }
            }
        }
    }

    // epilogue: bias + PReLU + store
    float4 bv0 = *(const float4*)(bl + tx * 8);
    float4 bv1 = *(const float4*)(bl + tx * 8 + 4);
    float4 sv0 = *(const float4*)(slope + tx * 8);
    float4 sv1 = *(const float4*)(slope + tx * 8 + 4);
    #pragma unroll
    for (int r = 0; r < 4; ++r) {
        int rr = row0 + r;
        if (rr < rows) {
            float v[8];
            v[0] = acc[r][0] + bv0.x; v[1] = acc[r][1] + bv0.y;
            v[2] = acc[r][2] + bv0.z; v[3] = acc[r][3] + bv0.w;
            v[4] = acc[r][4] + bv1.x; v[5] = acc[r][5] + bv1.y;
            v[6] = acc[r][6] + bv1.z; v[7] = acc[r][7] + bv1.w;
            float s[8] = {sv0.x, sv0.y, sv0.z, sv0.w, sv1.x, sv1.y, sv1.z, sv1.w};
            #pragma unroll
            for (int j = 0; j < 8; ++j) v[j] = v[j] > 0.f ? v[j] : s[j] * v[j];
            float4 o0 = make_float4(v[0], v[1], v[2], v[3]);
            float4 o1 = make_float4(v[4], v[5], v[6], v[7]);
            *(float4*)(out + rr * C + tx * 8) = o0;
            *(float4*)(out + rr * C + tx * 8 + 4) = o1;
        }
    }
}

// ---------------- launch ----------------

extern "C" void kernel_launch(void* const* d_in, const int* in_sizes, int n_in,
                              void* d_out, int out_size, void* d_ws, size_t ws_size,
                              hipStream_t stream) {
    const float* x   = (const float*)d_in[0];
    const int*   src = (const int*)d_in[1];          // edge_index row 0 (integer inputs arrive as int32)
    const int*   dst = src + NE;                     // edge_index row 1
    const float* Wl[3] = {(const float*)d_in[3], (const float*)d_in[7],  (const float*)d_in[11]};
    const float* bl[3] = {(const float*)d_in[4], (const float*)d_in[8],  (const float*)d_in[12]};
    const float* Wr[3] = {(const float*)d_in[5], (const float*)d_in[9],  (const float*)d_in[13]};
    const float* sl[3] = {(const float*)d_in[6], (const float*)d_in[10], (const float*)d_in[14]};

    // workspace layout (ints/floats, 4B units), ~80.8 MB total
    int*   deg     = (int*)d_ws;             // 50016
    int*   fill    = deg + 50016;            // 50016  (contiguous with deg for one memset)
    int*   row_ptr = fill + 50016;           // 50016 (uses 50001)
    int*   col     = row_ptr + 50016;        // 800000
    float* inv_deg = (float*)(col + 800000); // 50016
    float* agg     = inv_deg + 50016;        // 6.4M  (offset*4 is 16B-aligned)
    float* buf0    = agg + (size_t)NN * C;
    float* buf1    = buf0 + (size_t)NN * C;

    // zero deg + fill
    hipMemsetAsync(deg, 0, 2 * 50016 * sizeof(int), stream);

    const int EB = (NE + 255) / 256;
    count_kernel<<<EB, 256, 0, stream>>>(dst, deg, NE);
    scan_kernel<<<1, 256, 0, stream>>>(deg, row_ptr, inv_deg, NN);
    fill_kernel<<<EB, 256, 0, stream>>>(src, dst, row_ptr, fill, col, NE);

    int rows_out = out_size / C;             // 1024

    // layer 0: x -> buf0
    agg_kernel<<<(NN + 3) / 4, 256, 0, stream>>>(x, row_ptr, col, inv_deg, agg, NN);
    gemm_kernel<<<(NN + 63) / 64, 256, 0, stream>>>(agg, x, Wl[0], bl[0], Wr[0], sl[0], buf0, NN);

    // layer 1: buf0 -> buf1
    agg_kernel<<<(NN + 3) / 4, 256, 0, stream>>>(buf0, row_ptr, col, inv_deg, agg, NN);
    gemm_kernel<<<(NN + 63) / 64, 256, 0, stream>>>(agg, buf0, Wl[1], bl[1], Wr[1], sl[1], buf1, NN);

    // layer 2: only the first rows_out nodes are needed
    agg_kernel<<<(rows_out + 3) / 4, 256, 0, stream>>>(buf1, row_ptr, col, inv_deg, agg, rows_out);
    gemm_kernel<<<(rows_out + 63) / 64, 256, 0, stream>>>(agg, buf1, Wl[2], bl[2], Wr[2], sl[2],
                                                          (float*)d_out, rows_out);
}

// Round 2
// 469.955 us; speedup vs baseline: 1.2735x; 1.2735x over previous
//
#include <hip/hip_runtime.h>

#define NN 50000
#define NE 800000
#define C 128
#define SCAN_BLOCKS ((NN + 255) / 256)   // 196

// ---------------- preprocessing: build CSR (dst -> list of src) ----------------

__global__ void count_kernel(const int* __restrict__ dst, int* __restrict__ deg, int n_edges) {
    int e = blockIdx.x * blockDim.x + threadIdx.x;
    if (e < n_edges) atomicAdd(&deg[dst[e]], 1);
}

// stage 1: intra-block exclusive scan of deg -> row_ptr (block-local), block sum -> bsum,
// and inv_deg = 1/max(deg,1)
__global__ __launch_bounds__(256)
void scan1_kernel(const int* __restrict__ deg, int* __restrict__ row_ptr,
                  float* __restrict__ inv_deg, int* __restrict__ bsum, int n) {
    __shared__ int wsum[4];
    __shared__ int wpre[4];
    int t = threadIdx.x, lane = t & 63, w = t >> 6;
    int i = blockIdx.x * 256 + t;
    int v = (i < n) ? deg[i] : 0;
    int s = v;
    #pragma unroll
    for (int off = 1; off < 64; off <<= 1) {
        int y = __shfl_up(s, off, 64);
        if (lane >= off) s += y;
    }
    if (lane == 63) wsum[w] = s;
    __syncthreads();
    if (t == 0) {
        int acc = 0;
        #pragma unroll
        for (int j = 0; j < 4; ++j) { wpre[j] = acc; acc += wsum[j]; }
        bsum[blockIdx.x] = acc;
    }
    __syncthreads();
    if (i < n) {
        row_ptr[i] = wpre[w] + (s - v);          // block-local exclusive
        inv_deg[i] = 1.0f / (float)max(v, 1);
    }
}

// stage 2: single block scans the 196 block sums -> exclusive block offsets; writes total
__global__ __launch_bounds__(256)
void scan2_kernel(const int* __restrict__ bsum, int* __restrict__ boff,
                  int* __restrict__ row_ptr, int nb, int n) {
    __shared__ int wsum[4];
    __shared__ int wpre[4];
    int t = threadIdx.x, lane = t & 63, w = t >> 6;
    int v = (t < nb) ? bsum[t] : 0;
    int s = v;
    #pragma unroll
    for (int off = 1; off < 64; off <<= 1) {
        int y = __shfl_up(s, off, 64);
        if (lane >= off) s += y;
    }
    if (lane == 63) wsum[w] = s;
    __syncthreads();
    if (t == 0) {
        int acc = 0;
        #pragma unroll
        for (int j = 0; j < 4; ++j) { wpre[j] = acc; acc += wsum[j]; }
        row_ptr[n] = acc;                        // total == NE
    }
    __syncthreads();
    if (t < nb) boff[t] = wpre[w] + (s - v);     // exclusive across blocks
}

// stage 3: add block offsets
__global__ __launch_bounds__(256)
void scan3_kernel(int* __restrict__ row_ptr, const int* __restrict__ boff, int n) {
    int i = blockIdx.x * 256 + threadIdx.x;
    if (i < n) row_ptr[i] += boff[blockIdx.x];
}

__global__ void fill_kernel(const int* __restrict__ src, const int* __restrict__ dst,
                            const int* __restrict__ row_ptr, int* __restrict__ fill,
                            int* __restrict__ col, int n_edges) {
    int e = blockIdx.x * blockDim.x + threadIdx.x;
    if (e < n_edges) {
        int d = dst[e];
        int p = atomicAdd(&fill[d], 1);
        col[row_ptr[d] + p] = src[e];
    }
}

// ---------------- mean aggregation: one wave per node ----------------

__global__ __launch_bounds__(256)
void agg_kernel(const float* __restrict__ x, const int* __restrict__ row_ptr,
                const int* __restrict__ col, const float* __restrict__ inv_deg,
                float* __restrict__ agg, int nodes) {
    int wave = (blockIdx.x * blockDim.x + threadIdx.x) >> 6;
    int lane = threadIdx.x & 63;
    if (wave >= nodes) return;
    int start = row_ptr[wave], end = row_ptr[wave + 1];
    int off = lane * 2;
    float ax = 0.f, ay = 0.f;
    int e = start;
    for (; e + 1 < end; e += 2) {
        int s0 = col[e], s1 = col[e + 1];
        float2 v0 = *(const float2*)(x + s0 * C + off);
        float2 v1 = *(const float2*)(x + s1 * C + off);
        ax += v0.x + v1.x;
        ay += v0.y + v1.y;
    }
    if (e < end) {
        int s0 = col[e];
        float2 v0 = *(const float2*)(x + s0 * C + off);
        ax += v0.x;
        ay += v0.y;
    }
    float inv = inv_deg[wave];
    *(float2*)(agg + wave * C + off) = make_float2(ax * inv, ay * inv);
}

// ---------------- fused dual GEMM + bias + PReLU ----------------
// out[r][c] = prelu( dot(Ain[r], Wl[c]) + bl[c] + dot(Xin[r], Wr[c]), slope[c] )
// block = 256 threads, tile = 64 rows x 128 cols; thread tile = 4 rows x 8 cols.

__global__ __launch_bounds__(256, 2)
void gemm_kernel(const float* __restrict__ Ain, const float* __restrict__ Xin,
                 const float* __restrict__ Wl, const float* __restrict__ bl,
                 const float* __restrict__ Wr, const float* __restrict__ slope,
                 float* __restrict__ out, int rows) {
    __shared__ float WT[C * C]; // [k][c], 64 KB
    int t = threadIdx.x;
    int tx = t & 15;            // c0 = tx*8
    int ty = t >> 4;            // rows r = row0..row0+3
    int row0 = blockIdx.x * 64 + ty * 4;

    float acc[4][8];
    #pragma unroll
    for (int r = 0; r < 4; ++r)
        #pragma unroll
        for (int j = 0; j < 8; ++j) acc[r][j] = 0.f;

    #pragma unroll
    for (int mat = 0; mat < 2; ++mat) {
        const float* W = mat ? Wr : Wl;
        const float* A = mat ? Xin : Ain;
        __syncthreads();
        // stage W^T into LDS: consecutive threads -> consecutive c (conflict-free writes)
        #pragma unroll
        for (int j = 0; j < 16; ++j) {
            int i = t + j * 256;         // 0..4095 over (c, k4)
            int c = i & 127;
            int k4 = i >> 7;             // 0..31
            float4 wv = ((const float4*)W)[c * 32 + k4];
            int k = k4 * 4;
            WT[(k + 0) * C + c] = wv.x;
            WT[(k + 1) * C + c] = wv.y;
            WT[(k + 2) * C + c] = wv.z;
            WT[(k + 3) * C + c] = wv.w;
        }
        __syncthreads();

        const float* Ar0 = A + min(row0 + 0, rows - 1) * C;
        const float* Ar1 = A + min(row0 + 1, rows - 1) * C;
        const float* Ar2 = A + min(row0 + 2, rows - 1) * C;
        const float* Ar3 = A + min(row0 + 3, rows - 1) * C;

        for (int k = 0; k < C; k += 4) {
            float4 av[4];
            av[0] = *(const float4*)(Ar0 + k);
            av[1] = *(const float4*)(Ar1 + k);
            av[2] = *(const float4*)(Ar2 + k);
            av[3] = *(const float4*)(Ar3 + k);
            #pragma unroll
            for (int kk = 0; kk < 4; ++kk) {
                float4 w0 = *(const float4*)&WT[(k + kk) * C + tx * 8];
                float4 w1 = *(const float4*)&WT[(k + kk) * C + tx * 8 + 4];
                #pragma unroll
                for (int r = 0; r < 4; ++r) {
                    float a = (kk == 0) ? av[r].x : (kk == 1) ? av[r].y
                            : (kk == 2) ? av[r].z : av[r].w;
                    acc[r][0] += a * w0.x;
                    acc[r][1] += a * w0.y;
                    acc[r][2] += a * w0.z;
                    acc[r][3] += a * w0.w;
                    acc[r][4] += a * w1.x;
                    acc[r][5] += a * w1.y;
                    acc[r][6] += a * w1.z;
                    acc[r][7] += a * w1.w;
                }
            }
        }
    }

    // epilogue: bias + PReLU + store
    float4 bv0 = *(const float4*)(bl + tx * 8);
    float4 bv1 = *(const float4*)(bl + tx * 8 + 4);
    float4 sv0 = *(const float4*)(slope + tx * 8);
    float4 sv1 = *(const float4*)(slope + tx * 8 + 4);
    #pragma unroll
    for (int r = 0; r < 4; ++r) {
        int rr = row0 + r;
        if (rr < rows) {
            float v[8];
            v[0] = acc[r][0] + bv0.x; v[1] = acc[r][1] + bv0.y;
            v[2] = acc[r][2] + bv0.z; v[3] = acc[r][3] + bv0.w;
            v[4] = acc[r][4] + bv1.x; v[5] = acc[r][5] + bv1.y;
            v[6] = acc[r][6] + bv1.z; v[7] = acc[r][7] + bv1.w;
            float s[8] = {sv0.x, sv0.y, sv0.z, sv0.w, sv1.x, sv1.y, sv1.z, sv1.w};
            #pragma unroll
            for (int j = 0; j < 8; ++j) v[j] = v[j] > 0.f ? v[j] : s[j] * v[j];
            float4 o0 = make_float4(v[0], v[1], v[2], v[3]);
            float4 o1 = make_float4(v[4], v[5], v[6], v[7]);
            *(float4*)(out + rr * C + tx * 8) = o0;
            *(float4*)(out + rr * C + tx * 8 + 4) = o1;
        }
    }
}

// ---------------- launch ----------------

extern "C" void kernel_launch(void* const* d_in, const int* in_sizes, int n_in,
                              void* d_out, int out_size, void* d_ws, size_t ws_size,
                              hipStream_t stream) {
    const float* x   = (const float*)d_in[0];
    const int*   src = (const int*)d_in[1];          // edge_index row 0 (integer inputs arrive as int32)
    const int*   dst = src + NE;                     // edge_index row 1
    const float* Wl[3] = {(const float*)d_in[3], (const float*)d_in[7],  (const float*)d_in[11]};
    const float* bl[3] = {(const float*)d_in[4], (const float*)d_in[8],  (const float*)d_in[12]};
    const float* Wr[3] = {(const float*)d_in[5], (const float*)d_in[9],  (const float*)d_in[13]};
    const float* sl[3] = {(const float*)d_in[6], (const float*)d_in[10], (const float*)d_in[14]};

    // workspace layout (ints/floats, 4B units)
    int*   deg     = (int*)d_ws;             // 50016
    int*   fill    = deg + 50016;            // 50016  (contiguous with deg for one memset)
    int*   row_ptr = fill + 50016;           // 50016 (uses 50001)
    int*   col     = row_ptr + 50016;        // 800000
    float* inv_deg = (float*)(col + 800000); // 50016
    int*   bsum    = (int*)(inv_deg + 50016);// 256
    int*   boff    = bsum + 256;             // 256
    float* agg     = (float*)(boff + 256);   // 6.4M floats (offset*4 stays 16B-aligned)
    float* buf0    = agg + (size_t)NN * C;
    float* buf1    = buf0 + (size_t)NN * C;

    // zero deg + fill
    hipMemsetAsync(deg, 0, 2 * 50016 * sizeof(int), stream);

    const int EB = (NE + 255) / 256;
    count_kernel<<<EB, 256, 0, stream>>>(dst, deg, NE);
    scan1_kernel<<<SCAN_BLOCKS, 256, 0, stream>>>(deg, row_ptr, inv_deg, bsum, NN);
    scan2_kernel<<<1, 256, 0, stream>>>(bsum, boff, row_ptr, SCAN_BLOCKS, NN);
    scan3_kernel<<<SCAN_BLOCKS, 256, 0, stream>>>(row_ptr, boff, NN);
    fill_kernel<<<EB, 256, 0, stream>>>(src, dst, row_ptr, fill, col, NE);

    int rows_out = out_size / C;             // 1024

    // layer 0: x -> buf0
    agg_kernel<<<(NN + 3) / 4, 256, 0, stream>>>(x, row_ptr, col, inv_deg, agg, NN);
    gemm_kernel<<<(NN + 63) / 64, 256, 0, stream>>>(agg, x, Wl[0], bl[0], Wr[0], sl[0], buf0, NN);

    // layer 1: buf0 -> buf1
    agg_kernel<<<(NN + 3) / 4, 256, 0, stream>>>(buf0, row_ptr, col, inv_deg, agg, NN);
    gemm_kernel<<<(NN + 63) / 64, 256, 0, stream>>>(agg, buf0, Wl[1], bl[1], Wr[1], sl[1], buf1, NN);

    // layer 2: only the first rows_out nodes are needed
    agg_kernel<<<(rows_out + 3) / 4, 256, 0, stream>>>(buf1, row_ptr, col, inv_deg, agg, rows_out);
    gemm_kernel<<<(rows_out + 63) / 64, 256, 0, stream>>>(agg, buf1, Wl[2], bl[2], Wr[2], sl[2],
                                                          (float*)d_out, rows_out);
}

// Round 3
// 402.860 us; speedup vs baseline: 1.4856x; 1.1665x over previous
//
#include <hip/hip_runtime.h>

#define NN 50000
#define NE 800000
#define C 128
#define SCAN_BLOCKS ((NN + 255) / 256)   // 196
#define ASTRIDE 136                       // bf16 elems per LDS A row (16B-aligned, 4-bank row shift)

typedef __attribute__((ext_vector_type(8))) short bf16x8;
typedef __attribute__((ext_vector_type(4))) float f32x4;

__device__ inline unsigned short bf16_rn(float f) {
    unsigned u = __builtin_bit_cast(unsigned, f);
    u += 0x7FFF + ((u >> 16) & 1);
    return (unsigned short)(u >> 16);
}
__device__ inline void split_bf16(float f, unsigned short& hi, unsigned short& lo) {
    hi = bf16_rn(f);
    float hif = __builtin_bit_cast(float, (unsigned)hi << 16);
    lo = bf16_rn(f - hif);               // exact residual captured to ~2^-17 rel
}

// ---------------- preprocessing: build CSR (dst -> list of src) ----------------

__global__ void count_kernel(const int* __restrict__ dst, int* __restrict__ deg, int n_edges) {
    int e = blockIdx.x * blockDim.x + threadIdx.x;
    if (e < n_edges) atomicAdd(&deg[dst[e]], 1);
}

__global__ __launch_bounds__(256)
void scan1_kernel(const int* __restrict__ deg, int* __restrict__ row_ptr,
                  float* __restrict__ inv_deg, int* __restrict__ bsum, int n) {
    __shared__ int wsum[4];
    __shared__ int wpre[4];
    int t = threadIdx.x, lane = t & 63, w = t >> 6;
    int i = blockIdx.x * 256 + t;
    int v = (i < n) ? deg[i] : 0;
    int s = v;
    #pragma unroll
    for (int off = 1; off < 64; off <<= 1) {
        int y = __shfl_up(s, off, 64);
        if (lane >= off) s += y;
    }
    if (lane == 63) wsum[w] = s;
    __syncthreads();
    if (t == 0) {
        int acc = 0;
        #pragma unroll
        for (int j = 0; j < 4; ++j) { wpre[j] = acc; acc += wsum[j]; }
        bsum[blockIdx.x] = acc;
    }
    __syncthreads();
    if (i < n) {
        row_ptr[i] = wpre[w] + (s - v);
        inv_deg[i] = 1.0f / (float)max(v, 1);
    }
}

__global__ __launch_bounds__(256)
void scan2_kernel(const int* __restrict__ bsum, int* __restrict__ boff,
                  int* __restrict__ row_ptr, int nb, int n) {
    __shared__ int wsum[4];
    __shared__ int wpre[4];
    int t = threadIdx.x, lane = t & 63, w = t >> 6;
    int v = (t < nb) ? bsum[t] : 0;
    int s = v;
    #pragma unroll
    for (int off = 1; off < 64; off <<= 1) {
        int y = __shfl_up(s, off, 64);
        if (lane >= off) s += y;
    }
    if (lane == 63) wsum[w] = s;
    __syncthreads();
    if (t == 0) {
        int acc = 0;
        #pragma unroll
        for (int j = 0; j < 4; ++j) { wpre[j] = acc; acc += wsum[j]; }
        row_ptr[n] = acc;
    }
    __syncthreads();
    if (t < nb) boff[t] = wpre[w] + (s - v);
}

__global__ __launch_bounds__(256)
void scan3_kernel(int* __restrict__ row_ptr, const int* __restrict__ boff, int n) {
    int i = blockIdx.x * 256 + threadIdx.x;
    if (i < n) row_ptr[i] += boff[blockIdx.x];
}

__global__ void fill_kernel(const int* __restrict__ src, const int* __restrict__ dst,
                            const int* __restrict__ row_ptr, int* __restrict__ fill,
                            int* __restrict__ col, int n_edges) {
    int e = blockIdx.x * blockDim.x + threadIdx.x;
    if (e < n_edges) {
        int d = dst[e];
        int p = atomicAdd(&fill[d], 1);
        col[row_ptr[d] + p] = src[e];
    }
}

// ---------------- mean aggregation: one wave per node ----------------

__global__ __launch_bounds__(256)
void agg_kernel(const float* __restrict__ x, const int* __restrict__ row_ptr,
                const int* __restrict__ col, const float* __restrict__ inv_deg,
                float* __restrict__ agg, int nodes) {
    int wave = (blockIdx.x * blockDim.x + threadIdx.x) >> 6;
    int lane = threadIdx.x & 63;
    if (wave >= nodes) return;
    int start = row_ptr[wave], end = row_ptr[wave + 1];
    int off = lane * 2;
    float ax = 0.f, ay = 0.f;
    int e = start;
    for (; e + 1 < end; e += 2) {
        int s0 = col[e], s1 = col[e + 1];
        float2 v0 = *(const float2*)(x + s0 * C + off);
        float2 v1 = *(const float2*)(x + s1 * C + off);
        ax += v0.x + v1.x;
        ay += v0.y + v1.y;
    }
    if (e < end) {
        int s0 = col[e];
        float2 v0 = *(const float2*)(x + s0 * C + off);
        ax += v0.x;
        ay += v0.y;
    }
    float inv = inv_deg[wave];
    *(float2*)(agg + wave * C + off) = make_float2(ax * inv, ay * inv);
}

// ---------------- fused dual GEMM + bias + PReLU via split-bf16 MFMA ----------------
// out = prelu( Ain@Wl.T + bl + Xin@Wr.T ), fp32-accurate via 3 bf16 products per mat.
// block = 256 threads (4 waves), tile = 64 rows x 128 cols; wave = 32-col strip.
// W frags in registers (per-wave cols only); A hi/lo staged in LDS.

__global__ __launch_bounds__(256, 3)
void gemm_kernel(const float* __restrict__ Ain, const float* __restrict__ Xin,
                 const float* __restrict__ Wl, const float* __restrict__ bl,
                 const float* __restrict__ Wr, const float* __restrict__ slope,
                 float* __restrict__ out, int rows) {
    __shared__ unsigned short Ahi[64 * ASTRIDE];   // 17408 B
    __shared__ unsigned short Alo[64 * ASTRIDE];   // 17408 B
    int t = threadIdx.x;
    int lane = t & 63;
    int w = t >> 6;             // wave -> cols [w*32, w*32+32)
    int l = lane & 15;
    int q = lane >> 4;
    int row0 = blockIdx.x * 64;

    f32x4 acc[4][2];
    #pragma unroll
    for (int mt = 0; mt < 4; ++mt)
        #pragma unroll
        for (int nt = 0; nt < 2; ++nt)
            acc[mt][nt] = (f32x4){0.f, 0.f, 0.f, 0.f};

    #pragma unroll
    for (int mat = 0; mat < 2; ++mat) {
        const float* A = mat ? Xin : Ain;
        const float* W = mat ? Wr : Wl;

        // ---- W fragments (hi/lo) into registers: B[k][n] frag, n = lane&15, k = q*8+j ----
        bf16x8 bhi[2][4], blo[2][4];
        #pragma unroll
        for (int nt = 0; nt < 2; ++nt) {
            int n = w * 32 + nt * 16 + l;
            const float* wp = W + n * C + q * 8;
            #pragma unroll
            for (int kb = 0; kb < 4; ++kb) {
                f32x4 w0 = *(const f32x4*)(wp + kb * 32);
                f32x4 w1 = *(const f32x4*)(wp + kb * 32 + 4);
                float f[8] = {w0.x, w0.y, w0.z, w0.w, w1.x, w1.y, w1.z, w1.w};
                bf16x8 h, o;
                #pragma unroll
                for (int j = 0; j < 8; ++j) {
                    unsigned short hh, ll;
                    split_bf16(f[j], hh, ll);
                    h[j] = (short)hh;
                    o[j] = (short)ll;
                }
                bhi[nt][kb] = h;
                blo[nt][kb] = o;
            }
        }

        // ---- stage A tile (64 x 128) as hi/lo bf16 into LDS ----
        __syncthreads();                 // protect previous mat's frag reads
        {
            int ar = t >> 2;             // row 0..63
            int aq = t & 3;              // k quarter: [aq*32, aq*32+32)
            int r = min(row0 + ar, rows - 1);
            const float* ap = A + (size_t)r * C + aq * 32;
            unsigned short* dh = Ahi + ar * ASTRIDE + aq * 32;
            unsigned short* dl = Alo + ar * ASTRIDE + aq * 32;
            #pragma unroll
            for (int i = 0; i < 8; ++i) {
                f32x4 v = *(const f32x4*)(ap + i * 4);
                unsigned short h0, h1, h2, h3, l0, l1, l2, l3;
                split_bf16(v.x, h0, l0);
                split_bf16(v.y, h1, l1);
                split_bf16(v.z, h2, l2);
                split_bf16(v.w, h3, l3);
                *(uint2*)(dh + i * 4) = make_uint2((unsigned)h0 | ((unsigned)h1 << 16),
                                                   (unsigned)h2 | ((unsigned)h3 << 16));
                *(uint2*)(dl + i * 4) = make_uint2((unsigned)l0 | ((unsigned)l1 << 16),
                                                   (unsigned)l2 | ((unsigned)l3 << 16));
            }
        }
        __syncthreads();

        // ---- K loop: 4 k-blocks x 4 m-tiles x 2 n-tiles x 3 products ----
        #pragma unroll
        for (int kb = 0; kb < 4; ++kb) {
            #pragma unroll
            for (int mt = 0; mt < 4; ++mt) {
                int off = (mt * 16 + l) * ASTRIDE + kb * 32 + q * 8;
                bf16x8 ahi = *(const bf16x8*)(Ahi + off);
                bf16x8 alo = *(const bf16x8*)(Alo + off);
                #pragma unroll
                for (int nt = 0; nt < 2; ++nt) {
                    acc[mt][nt] = __builtin_amdgcn_mfma_f32_16x16x32_bf16(ahi, bhi[nt][kb], acc[mt][nt], 0, 0, 0);
                    acc[mt][nt] = __builtin_amdgcn_mfma_f32_16x16x32_bf16(alo, bhi[nt][kb], acc[mt][nt], 0, 0, 0);
                    acc[mt][nt] = __builtin_amdgcn_mfma_f32_16x16x32_bf16(ahi, blo[nt][kb], acc[mt][nt], 0, 0, 0);
                }
            }
        }
    }

    // ---- epilogue: bias + PReLU + store (C/D: col = lane&15, row = q*4 + reg) ----
    #pragma unroll
    for (int nt = 0; nt < 2; ++nt) {
        int n = w * 32 + nt * 16 + l;
        float b = bl[n], s = slope[n];
        #pragma unroll
        for (int mt = 0; mt < 4; ++mt) {
            #pragma unroll
            for (int rg = 0; rg < 4; ++rg) {
                int r = row0 + mt * 16 + q * 4 + rg;
                if (r < rows) {
                    float v = acc[mt][nt][rg] + b;
                    out[(size_t)r * C + n] = v > 0.f ? v : s * v;
                }
            }
        }
    }
}

// ---------------- launch ----------------

extern "C" void kernel_launch(void* const* d_in, const int* in_sizes, int n_in,
                              void* d_out, int out_size, void* d_ws, size_t ws_size,
                              hipStream_t stream) {
    const float* x   = (const float*)d_in[0];
    const int*   src = (const int*)d_in[1];
    const int*   dst = src + NE;
    const float* Wl[3] = {(const float*)d_in[3], (const float*)d_in[7],  (const float*)d_in[11]};
    const float* bl[3] = {(const float*)d_in[4], (const float*)d_in[8],  (const float*)d_in[12]};
    const float* Wr[3] = {(const float*)d_in[5], (const float*)d_in[9],  (const float*)d_in[13]};
    const float* sl[3] = {(const float*)d_in[6], (const float*)d_in[10], (const float*)d_in[14]};

    int*   deg     = (int*)d_ws;             // 50016
    int*   fill    = deg + 50016;            // 50016
    int*   row_ptr = fill + 50016;           // 50016
    int*   col     = row_ptr + 50016;        // 800000
    float* inv_deg = (float*)(col + 800000); // 50016
    int*   bsum    = (int*)(inv_deg + 50016);// 256
    int*   boff    = bsum + 256;             // 256
    float* agg     = (float*)(boff + 256);
    float* buf0    = agg + (size_t)NN * C;
    float* buf1    = buf0 + (size_t)NN * C;

    hipMemsetAsync(deg, 0, 2 * 50016 * sizeof(int), stream);

    const int EB = (NE + 255) / 256;
    count_kernel<<<EB, 256, 0, stream>>>(dst, deg, NE);
    scan1_kernel<<<SCAN_BLOCKS, 256, 0, stream>>>(deg, row_ptr, inv_deg, bsum, NN);
    scan2_kernel<<<1, 256, 0, stream>>>(bsum, boff, row_ptr, SCAN_BLOCKS, NN);
    scan3_kernel<<<SCAN_BLOCKS, 256, 0, stream>>>(row_ptr, boff, NN);
    fill_kernel<<<EB, 256, 0, stream>>>(src, dst, row_ptr, fill, col, NE);

    int rows_out = out_size / C;             // 1024

    agg_kernel<<<(NN + 3) / 4, 256, 0, stream>>>(x, row_ptr, col, inv_deg, agg, NN);
    gemm_kernel<<<(NN + 63) / 64, 256, 0, stream>>>(agg, x, Wl[0], bl[0], Wr[0], sl[0], buf0, NN);

    agg_kernel<<<(NN + 3) / 4, 256, 0, stream>>>(buf0, row_ptr, col, inv_deg, agg, NN);
    gemm_kernel<<<(NN + 63) / 64, 256, 0, stream>>>(agg, buf0, Wl[1], bl[1], Wr[1], sl[1], buf1, NN);

    agg_kernel<<<(rows_out + 3) / 4, 256, 0, stream>>>(buf1, row_ptr, col, inv_deg, agg, rows_out);
    gemm_kernel<<<(rows_out + 63) / 64, 256, 0, stream>>>(agg, buf1, Wl[2], bl[2], Wr[2], sl[2],
                                                          (float*)d_out, rows_out);
}

// Round 5
// 357.853 us; speedup vs baseline: 1.6725x; 1.1258x over previous
//
#include <hip/hip_runtime.h>

#define NN 50000
#define NE 800000
#define C 128
#define SCAN_BLOCKS ((NN + 255) / 256)   // 196
#define ASTRIDE 136                       // bf16 elems per LDS A row (16B-aligned rows, bank shift)

typedef __attribute__((ext_vector_type(8))) short bf16x8;
typedef __attribute__((ext_vector_type(4))) float f32x4;
typedef unsigned short ushort;

__device__ inline ushort bf16_rn(float f) {
    unsigned u = __builtin_bit_cast(unsigned, f);
    u += 0x7FFF + ((u >> 16) & 1);
    return (ushort)(u >> 16);
}
__device__ inline void split_bf16(float f, ushort& hi, ushort& lo) {
    hi = bf16_rn(f);
    float hif = __builtin_bit_cast(float, (unsigned)hi << 16);
    lo = bf16_rn(f - hif);               // residual, ~2^-17 rel total
}

// ---------------- preprocessing: build CSR (dst -> list of src) ----------------

__global__ void count_kernel(const int* __restrict__ dst, int* __restrict__ deg, int n_edges) {
    int e = blockIdx.x * blockDim.x + threadIdx.x;
    if (e < n_edges) atomicAdd(&deg[dst[e]], 1);
}

__global__ __launch_bounds__(256)
void scan1_kernel(const int* __restrict__ deg, int* __restrict__ row_ptr,
                  float* __restrict__ inv_deg, int* __restrict__ bsum, int n) {
    __shared__ int wsum[4];
    __shared__ int wpre[4];
    int t = threadIdx.x, lane = t & 63, w = t >> 6;
    int i = blockIdx.x * 256 + t;
    int v = (i < n) ? deg[i] : 0;
    int s = v;
    #pragma unroll
    for (int off = 1; off < 64; off <<= 1) {
        int y = __shfl_up(s, off, 64);
        if (lane >= off) s += y;
    }
    if (lane == 63) wsum[w] = s;
    __syncthreads();
    if (t == 0) {
        int acc = 0;
        #pragma unroll
        for (int j = 0; j < 4; ++j) { wpre[j] = acc; acc += wsum[j]; }
        bsum[blockIdx.x] = acc;
    }
    __syncthreads();
    if (i < n) {
        row_ptr[i] = wpre[w] + (s - v);
        inv_deg[i] = 1.0f / (float)max(v, 1);
    }
}

__global__ __launch_bounds__(256)
void scan2_kernel(const int* __restrict__ bsum, int* __restrict__ boff,
                  int* __restrict__ row_ptr, int nb, int n) {
    __shared__ int wsum[4];
    __shared__ int wpre[4];
    int t = threadIdx.x, lane = t & 63, w = t >> 6;
    int v = (t < nb) ? bsum[t] : 0;
    int s = v;
    #pragma unroll
    for (int off = 1; off < 64; off <<= 1) {
        int y = __shfl_up(s, off, 64);
        if (lane >= off) s += y;
    }
    if (lane == 63) wsum[w] = s;
    __syncthreads();
    if (t == 0) {
        int acc = 0;
        #pragma unroll
        for (int j = 0; j < 4; ++j) { wpre[j] = acc; acc += wsum[j]; }
        row_ptr[n] = acc;
    }
    __syncthreads();
    if (t < nb) boff[t] = wpre[w] + (s - v);
}

__global__ __launch_bounds__(256)
void scan3_kernel(int* __restrict__ row_ptr, const int* __restrict__ boff, int n) {
    int i = blockIdx.x * 256 + threadIdx.x;
    if (i < n) row_ptr[i] += boff[blockIdx.x];
}

__global__ void fill_kernel(const int* __restrict__ src, const int* __restrict__ dst,
                            const int* __restrict__ row_ptr, int* __restrict__ fill,
                            int* __restrict__ col, int n_edges) {
    int e = blockIdx.x * blockDim.x + threadIdx.x;
    if (e < n_edges) {
        int d = dst[e];
        int p = atomicAdd(&fill[d], 1);
        col[row_ptr[d] + p] = src[e];
    }
}

// ---------------- split fp32 -> bf16 hi/lo shadow arrays ----------------

__global__ __launch_bounds__(256)
void split_kernel(const float* __restrict__ in, ushort* __restrict__ h,
                  ushort* __restrict__ l, int n4) {
    int i = blockIdx.x * 256 + threadIdx.x;
    if (i >= n4) return;
    f32x4 v = ((const f32x4*)in)[i];
    ushort h0, h1, h2, h3, l0, l1, l2, l3;
    split_bf16(v.x, h0, l0);
    split_bf16(v.y, h1, l1);
    split_bf16(v.z, h2, l2);
    split_bf16(v.w, h3, l3);
    *(uint2*)(h + i * 4) = make_uint2((unsigned)h0 | ((unsigned)h1 << 16),
                                      (unsigned)h2 | ((unsigned)h3 << 16));
    *(uint2*)(l + i * 4) = make_uint2((unsigned)l0 | ((unsigned)l1 << 16),
                                      (unsigned)l2 | ((unsigned)l3 << 16));
}

// ---------------- mean aggregation: one wave per node, bf16-hi gather ----------------
// lane loads one uint = 2 packed bf16 channels -> 256B coalesced row per edge.

__global__ __launch_bounds__(256)
void agg_kernel(const ushort* __restrict__ xh, const int* __restrict__ row_ptr,
                const int* __restrict__ col, const float* __restrict__ inv_deg,
                float* __restrict__ agg, int nodes) {
    int node = (blockIdx.x * blockDim.x + threadIdx.x) >> 6;
    int lane = threadIdx.x & 63;
    if (node >= nodes) return;
    int start = row_ptr[node], end = row_ptr[node + 1];
    const unsigned* xr = (const unsigned*)xh;   // row = 64 uints
    float ax = 0.f, ay = 0.f;
    int e = start;
    for (; e + 3 < end; e += 4) {
        int s0 = col[e], s1 = col[e + 1], s2 = col[e + 2], s3 = col[e + 3];
        unsigned u0 = xr[(size_t)s0 * 64 + lane];
        unsigned u1 = xr[(size_t)s1 * 64 + lane];
        unsigned u2 = xr[(size_t)s2 * 64 + lane];
        unsigned u3 = xr[(size_t)s3 * 64 + lane];
        ax += __builtin_bit_cast(float, u0 << 16) + __builtin_bit_cast(float, u1 << 16)
            + __builtin_bit_cast(float, u2 << 16) + __builtin_bit_cast(float, u3 << 16);
        ay += __builtin_bit_cast(float, u0 & 0xFFFF0000u) + __builtin_bit_cast(float, u1 & 0xFFFF0000u)
            + __builtin_bit_cast(float, u2 & 0xFFFF0000u) + __builtin_bit_cast(float, u3 & 0xFFFF0000u);
    }
    for (; e < end; ++e) {
        unsigned u = xr[(size_t)col[e] * 64 + lane];
        ax += __builtin_bit_cast(float, u << 16);
        ay += __builtin_bit_cast(float, u & 0xFFFF0000u);
    }
    float inv = inv_deg[node];
    *(float2*)(agg + (size_t)node * C + lane * 2) = make_float2(ax * inv, ay * inv);
}

// ---------------- fused dual GEMM + bias + PReLU via split-bf16 MFMA ----------------
// out = prelu( Ain@Wl.T + bl + X@Wr.T ); Ain fp32 (split in-kernel), X pre-split hi/lo.
// block = 256 (4 waves), tile 64 rows x 128 cols; wave = 32-col strip; W frags in regs.

__global__ __launch_bounds__(256, 3)
void gemm_kernel(const float* __restrict__ Ain,
                 const ushort* __restrict__ Xh, const ushort* __restrict__ Xl,
                 const float* __restrict__ Wl, const float* __restrict__ bl,
                 const float* __restrict__ Wr, const float* __restrict__ slope,
                 float* __restrict__ outf, ushort* __restrict__ outh,
                 ushort* __restrict__ outl, int rows) {
    __shared__ ushort Ahi[64 * ASTRIDE];
    __shared__ ushort Alo[64 * ASTRIDE];
    int t = threadIdx.x;
    int lane = t & 63;
    int w = t >> 6;
    int l = lane & 15;
    int q = lane >> 4;
    int row0 = blockIdx.x * 64;

    f32x4 acc[4][2];
    #pragma unroll
    for (int mt = 0; mt < 4; ++mt)
        #pragma unroll
        for (int nt = 0; nt < 2; ++nt)
            acc[mt][nt] = (f32x4){0.f, 0.f, 0.f, 0.f};

    #pragma unroll
    for (int mat = 0; mat < 2; ++mat) {
        const float* W = mat ? Wr : Wl;

        // W fragments (hi/lo) into registers: B[k][n], n = lane&15, k = q*8+j
        bf16x8 bhi[2][4], blo[2][4];
        #pragma unroll
        for (int nt = 0; nt < 2; ++nt) {
            int n = w * 32 + nt * 16 + l;
            const float* wp = W + n * C + q * 8;
            #pragma unroll
            for (int kb = 0; kb < 4; ++kb) {
                f32x4 w0 = *(const f32x4*)(wp + kb * 32);
                f32x4 w1 = *(const f32x4*)(wp + kb * 32 + 4);
                float f[8] = {w0.x, w0.y, w0.z, w0.w, w1.x, w1.y, w1.z, w1.w};
                bf16x8 h, o;
                #pragma unroll
                for (int j = 0; j < 8; ++j) {
                    ushort hh, ll;
                    split_bf16(f[j], hh, ll);
                    h[j] = (short)hh;
                    o[j] = (short)ll;
                }
                bhi[nt][kb] = h;
                blo[nt][kb] = o;
            }
        }

        __syncthreads();                 // protect previous mat's frag reads
        int ar = t >> 2;                 // row 0..63
        int aq = t & 3;                  // k quarter: 32 ushorts
        int r = min(row0 + ar, rows - 1);
        ushort* dh = Ahi + ar * ASTRIDE + aq * 32;
        ushort* dl = Alo + ar * ASTRIDE + aq * 32;
        if (mat == 0) {
            const float* ap = Ain + (size_t)r * C + aq * 32;
            #pragma unroll
            for (int i = 0; i < 8; ++i) {
                f32x4 v = *(const f32x4*)(ap + i * 4);
                ushort h0, h1, h2, h3, l0, l1, l2, l3;
                split_bf16(v.x, h0, l0);
                split_bf16(v.y, h1, l1);
                split_bf16(v.z, h2, l2);
                split_bf16(v.w, h3, l3);
                *(uint2*)(dh + i * 4) = make_uint2((unsigned)h0 | ((unsigned)h1 << 16),
                                                   (unsigned)h2 | ((unsigned)h3 << 16));
                *(uint2*)(dl + i * 4) = make_uint2((unsigned)l0 | ((unsigned)l1 << 16),
                                                   (unsigned)l2 | ((unsigned)l3 << 16));
            }
        } else {
            const ushort* ph = Xh + (size_t)r * C + aq * 32;
            const ushort* pl = Xl + (size_t)r * C + aq * 32;
            #pragma unroll
            for (int i = 0; i < 4; ++i) {        // 4 x uint4 = 32 ushorts (R4 bug: was 2 x at wrong stride)
                *(uint4*)(dh + i * 8) = *(const uint4*)(ph + i * 8);
                *(uint4*)(dl + i * 8) = *(const uint4*)(pl + i * 8);
            }
        }
        __syncthreads();

        // K loop: 4 k-blocks x 4 m-tiles x 2 n-tiles x 3 products
        #pragma unroll
        for (int kb = 0; kb < 4; ++kb) {
            #pragma unroll
            for (int mt = 0; mt < 4; ++mt) {
                int off = (mt * 16 + l) * ASTRIDE + kb * 32 + q * 8;
                bf16x8 ahi = *(const bf16x8*)(Ahi + off);
                bf16x8 alo = *(const bf16x8*)(Alo + off);
                #pragma unroll
                for (int nt = 0; nt < 2; ++nt) {
                    acc[mt][nt] = __builtin_amdgcn_mfma_f32_16x16x32_bf16(ahi, bhi[nt][kb], acc[mt][nt], 0, 0, 0);
                    acc[mt][nt] = __builtin_amdgcn_mfma_f32_16x16x32_bf16(alo, bhi[nt][kb], acc[mt][nt], 0, 0, 0);
                    acc[mt][nt] = __builtin_amdgcn_mfma_f32_16x16x32_bf16(ahi, blo[nt][kb], acc[mt][nt], 0, 0, 0);
                }
            }
        }
    }

    // epilogue: bias + PReLU; write fp32 (final layer) or hi/lo (hidden layers)
    #pragma unroll
    for (int nt = 0; nt < 2; ++nt) {
        int n = w * 32 + nt * 16 + l;
        float b = bl[n], s = slope[n];
        #pragma unroll
        for (int mt = 0; mt < 4; ++mt) {
            #pragma unroll
            for (int rg = 0; rg < 4; ++rg) {
                int r = row0 + mt * 16 + q * 4 + rg;
                if (r < rows) {
                    float v = acc[mt][nt][rg] + b;
                    v = v > 0.f ? v : s * v;
                    if (outf) {
                        outf[(size_t)r * C + n] = v;
                    } else {
                        ushort hh, ll;
                        split_bf16(v, hh, ll);
                        outh[(size_t)r * C + n] = hh;
                        outl[(size_t)r * C + n] = ll;
                    }
                }
            }
        }
    }
}

// ---------------- launch ----------------

extern "C" void kernel_launch(void* const* d_in, const int* in_sizes, int n_in,
                              void* d_out, int out_size, void* d_ws, size_t ws_size,
                              hipStream_t stream) {
    const float* x   = (const float*)d_in[0];
    const int*   src = (const int*)d_in[1];
    const int*   dst = src + NE;
    const float* Wl[3] = {(const float*)d_in[3], (const float*)d_in[7],  (const float*)d_in[11]};
    const float* bl[3] = {(const float*)d_in[4], (const float*)d_in[8],  (const float*)d_in[12]};
    const float* Wr[3] = {(const float*)d_in[5], (const float*)d_in[9],  (const float*)d_in[13]};
    const float* sl[3] = {(const float*)d_in[6], (const float*)d_in[10], (const float*)d_in[14]};

    int*   deg     = (int*)d_ws;             // 50016
    int*   fill    = deg + 50016;            // 50016
    int*   row_ptr = fill + 50016;           // 50016
    int*   col     = row_ptr + 50016;        // 800000
    float* inv_deg = (float*)(col + 800000); // 50016
    int*   bsum    = (int*)(inv_deg + 50016);// 256
    int*   boff    = bsum + 256;             // 256
    float* agg     = (float*)(boff + 256);   // NN*C fp32 (16B-aligned)
    ushort* Ah     = (ushort*)(agg + (size_t)NN * C);   // ping hi
    ushort* Al     = Ah + (size_t)NN * C;               // ping lo
    ushort* Bh     = Al + (size_t)NN * C;               // pong hi
    ushort* Bl     = Bh + (size_t)NN * C;               // pong lo

    hipMemsetAsync(deg, 0, 2 * 50016 * sizeof(int), stream);

    const int EB = (NE + 255) / 256;
    count_kernel<<<EB, 256, 0, stream>>>(dst, deg, NE);
    scan1_kernel<<<SCAN_BLOCKS, 256, 0, stream>>>(deg, row_ptr, inv_deg, bsum, NN);
    scan2_kernel<<<1, 256, 0, stream>>>(bsum, boff, row_ptr, SCAN_BLOCKS, NN);
    scan3_kernel<<<SCAN_BLOCKS, 256, 0, stream>>>(row_ptr, boff, NN);
    fill_kernel<<<EB, 256, 0, stream>>>(src, dst, row_ptr, fill, col, NE);

    // split x into ping buffer (hi/lo)
    split_kernel<<<(NN * C / 4 + 255) / 256, 256, 0, stream>>>(x, Ah, Al, NN * C / 4);

    int rows_out = out_size / C;             // 1024

    // layer 0: A -> B
    agg_kernel<<<(NN + 3) / 4, 256, 0, stream>>>(Ah, row_ptr, col, inv_deg, agg, NN);
    gemm_kernel<<<(NN + 63) / 64, 256, 0, stream>>>(agg, Ah, Al, Wl[0], bl[0], Wr[0], sl[0],
                                                    nullptr, Bh, Bl, NN);

    // layer 1: B -> A
    agg_kernel<<<(NN + 3) / 4, 256, 0, stream>>>(Bh, row_ptr, col, inv_deg, agg, NN);
    gemm_kernel<<<(NN + 63) / 64, 256, 0, stream>>>(agg, Bh, Bl, Wl[1], bl[1], Wr[1], sl[1],
                                                    nullptr, Ah, Al, NN);

    // layer 2: A -> d_out (first rows_out nodes only)
    agg_kernel<<<(rows_out + 3) / 4, 256, 0, stream>>>(Ah, row_ptr, col, inv_deg, agg, rows_out);
    gemm_kernel<<<(rows_out + 63) / 64, 256, 0, stream>>>(agg, Ah, Al, Wl[2], bl[2], Wr[2], sl[2],
                                                          (float*)d_out, nullptr, nullptr, rows_out);
}

// Round 6
// 319.608 us; speedup vs baseline: 1.8726x; 1.1197x over previous
//
#include <hip/hip_runtime.h>

#define NN 50000
#define NE 800000
#define C 128
#define SCAN_BLOCKS ((NN + 255) / 256)   // 196
#define ASTRIDE 136                       // bf16 elems per LDS A row (16B-aligned rows, bank shift)

typedef __attribute__((ext_vector_type(8))) short bf16x8;
typedef __attribute__((ext_vector_type(4))) float f32x4;
typedef unsigned short ushort;

__device__ inline ushort bf16_rn(float f) {
    unsigned u = __builtin_bit_cast(unsigned, f);
    u += 0x7FFF + ((u >> 16) & 1);
    return (ushort)(u >> 16);
}
__device__ inline void split_bf16(float f, ushort& hi, ushort& lo) {
    hi = bf16_rn(f);
    float hif = __builtin_bit_cast(float, (unsigned)hi << 16);
    lo = bf16_rn(f - hif);               // residual, ~2^-17 rel total
}

// ---------------- preprocessing: build CSR (dst -> list of src) ----------------
// pass 1: degree count + per-edge slot (atomic return latency hidden by 4 chains/thread)

__global__ __launch_bounds__(256)
void count_pos_kernel(const int* __restrict__ dst, int* __restrict__ deg,
                      int* __restrict__ pos, int n_edges) {
    int e0 = (blockIdx.x * blockDim.x + threadIdx.x) * 4;
    if (e0 >= n_edges) return;
    int4 d4 = *(const int4*)(dst + e0);
    int p0 = atomicAdd(&deg[d4.x], 1);
    int p1 = atomicAdd(&deg[d4.y], 1);
    int p2 = atomicAdd(&deg[d4.z], 1);
    int p3 = atomicAdd(&deg[d4.w], 1);
    *(int4*)(pos + e0) = make_int4(p0, p1, p2, p3);
}

__global__ __launch_bounds__(256)
void scan1_kernel(const int* __restrict__ deg, int* __restrict__ row_ptr,
                  float* __restrict__ inv_deg, int* __restrict__ bsum, int n) {
    __shared__ int wsum[4];
    __shared__ int wpre[4];
    int t = threadIdx.x, lane = t & 63, w = t >> 6;
    int i = blockIdx.x * 256 + t;
    int v = (i < n) ? deg[i] : 0;
    int s = v;
    #pragma unroll
    for (int off = 1; off < 64; off <<= 1) {
        int y = __shfl_up(s, off, 64);
        if (lane >= off) s += y;
    }
    if (lane == 63) wsum[w] = s;
    __syncthreads();
    if (t == 0) {
        int acc = 0;
        #pragma unroll
        for (int j = 0; j < 4; ++j) { wpre[j] = acc; acc += wsum[j]; }
        bsum[blockIdx.x] = acc;
    }
    __syncthreads();
    if (i < n) {
        row_ptr[i] = wpre[w] + (s - v);
        inv_deg[i] = 1.0f / (float)max(v, 1);
    }
}

__global__ __launch_bounds__(256)
void scan2_kernel(const int* __restrict__ bsum, int* __restrict__ boff,
                  int* __restrict__ row_ptr, int nb, int n) {
    __shared__ int wsum[4];
    __shared__ int wpre[4];
    int t = threadIdx.x, lane = t & 63, w = t >> 6;
    int v = (t < nb) ? bsum[t] : 0;
    int s = v;
    #pragma unroll
    for (int off = 1; off < 64; off <<= 1) {
        int y = __shfl_up(s, off, 64);
        if (lane >= off) s += y;
    }
    if (lane == 63) wsum[w] = s;
    __syncthreads();
    if (t == 0) {
        int acc = 0;
        #pragma unroll
        for (int j = 0; j < 4; ++j) { wpre[j] = acc; acc += wsum[j]; }
        row_ptr[n] = acc;
    }
    __syncthreads();
    if (t < nb) boff[t] = wpre[w] + (s - v);
}

__global__ __launch_bounds__(256)
void scan3_kernel(int* __restrict__ row_ptr, const int* __restrict__ boff, int n) {
    int i = blockIdx.x * 256 + threadIdx.x;
    if (i < n) row_ptr[i] += boff[blockIdx.x];
}

// pass 2: placement, atomic-free (stores are fire-and-forget)

__global__ __launch_bounds__(256)
void fill2_kernel(const int* __restrict__ src, const int* __restrict__ dst,
                  const int* __restrict__ row_ptr, const int* __restrict__ pos,
                  int* __restrict__ col, int n_edges) {
    int e0 = (blockIdx.x * blockDim.x + threadIdx.x) * 4;
    if (e0 >= n_edges) return;
    int4 d4 = *(const int4*)(dst + e0);
    int4 s4 = *(const int4*)(src + e0);
    int4 p4 = *(const int4*)(pos + e0);
    col[row_ptr[d4.x] + p4.x] = s4.x;
    col[row_ptr[d4.y] + p4.y] = s4.y;
    col[row_ptr[d4.z] + p4.z] = s4.z;
    col[row_ptr[d4.w] + p4.w] = s4.w;
}

// ---------------- split fp32 -> bf16 hi/lo shadow arrays ----------------

__global__ __launch_bounds__(256)
void split_kernel(const float* __restrict__ in, ushort* __restrict__ h,
                  ushort* __restrict__ l, int n4) {
    int i = blockIdx.x * 256 + threadIdx.x;
    if (i >= n4) return;
    f32x4 v = ((const f32x4*)in)[i];
    ushort h0, h1, h2, h3, l0, l1, l2, l3;
    split_bf16(v.x, h0, l0);
    split_bf16(v.y, h1, l1);
    split_bf16(v.z, h2, l2);
    split_bf16(v.w, h3, l3);
    *(uint2*)(h + i * 4) = make_uint2((unsigned)h0 | ((unsigned)h1 << 16),
                                      (unsigned)h2 | ((unsigned)h3 << 16));
    *(uint2*)(l + i * 4) = make_uint2((unsigned)l0 | ((unsigned)l1 << 16),
                                      (unsigned)l2 | ((unsigned)l3 << 16));
}

// ---------------- mean aggregation: one wave per node, bf16-hi gather ----------------
// lane loads one uint = 2 packed bf16 channels; 8 edge-rows in flight for latency overlap.

__global__ __launch_bounds__(256)
void agg_kernel(const ushort* __restrict__ xh, const int* __restrict__ row_ptr,
                const int* __restrict__ col, const float* __restrict__ inv_deg,
                float* __restrict__ agg, int nodes) {
    int node = (blockIdx.x * blockDim.x + threadIdx.x) >> 6;
    int lane = threadIdx.x & 63;
    if (node >= nodes) return;
    int start = row_ptr[node], end = row_ptr[node + 1];
    const unsigned* xr = (const unsigned*)xh;   // row = 64 uints
    float ax = 0.f, ay = 0.f;
    int e = start;
    for (; e + 7 < end; e += 8) {
        unsigned u[8];
        #pragma unroll
        for (int j = 0; j < 8; ++j) u[j] = xr[(size_t)col[e + j] * 64 + lane];
        #pragma unroll
        for (int j = 0; j < 8; ++j) {
            ax += __builtin_bit_cast(float, u[j] << 16);
            ay += __builtin_bit_cast(float, u[j] & 0xFFFF0000u);
        }
    }
    for (; e + 1 < end; e += 2) {
        unsigned u0 = xr[(size_t)col[e] * 64 + lane];
        unsigned u1 = xr[(size_t)col[e + 1] * 64 + lane];
        ax += __builtin_bit_cast(float, u0 << 16) + __builtin_bit_cast(float, u1 << 16);
        ay += __builtin_bit_cast(float, u0 & 0xFFFF0000u) + __builtin_bit_cast(float, u1 & 0xFFFF0000u);
    }
    if (e < end) {
        unsigned u = xr[(size_t)col[e] * 64 + lane];
        ax += __builtin_bit_cast(float, u << 16);
        ay += __builtin_bit_cast(float, u & 0xFFFF0000u);
    }
    float inv = inv_deg[node];
    *(float2*)(agg + (size_t)node * C + lane * 2) = make_float2(ax * inv, ay * inv);
}

// ---------------- fused dual GEMM + bias + PReLU via split-bf16 MFMA ----------------
// out = prelu( Ain@Wl.T + bl + X@Wr.T ); Ain fp32 (split in-kernel), X pre-split hi/lo.
// block = 256 (4 waves), tile 64 rows x 128 cols; wave = 32-col strip; W frags in regs.

__global__ __launch_bounds__(256, 3)
void gemm_kernel(const float* __restrict__ Ain,
                 const ushort* __restrict__ Xh, const ushort* __restrict__ Xl,
                 const float* __restrict__ Wl, const float* __restrict__ bl,
                 const float* __restrict__ Wr, const float* __restrict__ slope,
                 float* __restrict__ outf, ushort* __restrict__ outh,
                 ushort* __restrict__ outl, int rows) {
    __shared__ ushort Ahi[64 * ASTRIDE];
    __shared__ ushort Alo[64 * ASTRIDE];
    int t = threadIdx.x;
    int lane = t & 63;
    int w = t >> 6;
    int l = lane & 15;
    int q = lane >> 4;
    int row0 = blockIdx.x * 64;

    f32x4 acc[4][2];
    #pragma unroll
    for (int mt = 0; mt < 4; ++mt)
        #pragma unroll
        for (int nt = 0; nt < 2; ++nt)
            acc[mt][nt] = (f32x4){0.f, 0.f, 0.f, 0.f};

    #pragma unroll
    for (int mat = 0; mat < 2; ++mat) {
        const float* W = mat ? Wr : Wl;

        // W fragments (hi/lo) into registers: B[k][n], n = lane&15, k = q*8+j
        bf16x8 bhi[2][4], blo[2][4];
        #pragma unroll
        for (int nt = 0; nt < 2; ++nt) {
            int n = w * 32 + nt * 16 + l;
            const float* wp = W + n * C + q * 8;
            #pragma unroll
            for (int kb = 0; kb < 4; ++kb) {
                f32x4 w0 = *(const f32x4*)(wp + kb * 32);
                f32x4 w1 = *(const f32x4*)(wp + kb * 32 + 4);
                float f[8] = {w0.x, w0.y, w0.z, w0.w, w1.x, w1.y, w1.z, w1.w};
                bf16x8 h, o;
                #pragma unroll
                for (int j = 0; j < 8; ++j) {
                    ushort hh, ll;
                    split_bf16(f[j], hh, ll);
                    h[j] = (short)hh;
                    o[j] = (short)ll;
                }
                bhi[nt][kb] = h;
                blo[nt][kb] = o;
            }
        }

        __syncthreads();                 // protect previous mat's frag reads
        int ar = t >> 2;                 // row 0..63
        int aq = t & 3;                  // k quarter: 32 ushorts
        int r = min(row0 + ar, rows - 1);
        ushort* dh = Ahi + ar * ASTRIDE + aq * 32;
        ushort* dl = Alo + ar * ASTRIDE + aq * 32;
        if (mat == 0) {
            const float* ap = Ain + (size_t)r * C + aq * 32;
            #pragma unroll
            for (int i = 0; i < 8; ++i) {
                f32x4 v = *(const f32x4*)(ap + i * 4);
                ushort h0, h1, h2, h3, l0, l1, l2, l3;
                split_bf16(v.x, h0, l0);
                split_bf16(v.y, h1, l1);
                split_bf16(v.z, h2, l2);
                split_bf16(v.w, h3, l3);
                *(uint2*)(dh + i * 4) = make_uint2((unsigned)h0 | ((unsigned)h1 << 16),
                                                   (unsigned)h2 | ((unsigned)h3 << 16));
                *(uint2*)(dl + i * 4) = make_uint2((unsigned)l0 | ((unsigned)l1 << 16),
                                                   (unsigned)l2 | ((unsigned)l3 << 16));
            }
        } else {
            const ushort* ph = Xh + (size_t)r * C + aq * 32;
            const ushort* pl = Xl + (size_t)r * C + aq * 32;
            #pragma unroll
            for (int i = 0; i < 4; ++i) {        // 4 x uint4 = 32 ushorts
                *(uint4*)(dh + i * 8) = *(const uint4*)(ph + i * 8);
                *(uint4*)(dl + i * 8) = *(const uint4*)(pl + i * 8);
            }
        }
        __syncthreads();

        // K loop: 4 k-blocks x 4 m-tiles x 2 n-tiles x 3 products
        #pragma unroll
        for (int kb = 0; kb < 4; ++kb) {
            #pragma unroll
            for (int mt = 0; mt < 4; ++mt) {
                int off = (mt * 16 + l) * ASTRIDE + kb * 32 + q * 8;
                bf16x8 ahi = *(const bf16x8*)(Ahi + off);
                bf16x8 alo = *(const bf16x8*)(Alo + off);
                #pragma unroll
                for (int nt = 0; nt < 2; ++nt) {
                    acc[mt][nt] = __builtin_amdgcn_mfma_f32_16x16x32_bf16(ahi, bhi[nt][kb], acc[mt][nt], 0, 0, 0);
                    acc[mt][nt] = __builtin_amdgcn_mfma_f32_16x16x32_bf16(alo, bhi[nt][kb], acc[mt][nt], 0, 0, 0);
                    acc[mt][nt] = __builtin_amdgcn_mfma_f32_16x16x32_bf16(ahi, blo[nt][kb], acc[mt][nt], 0, 0, 0);
                }
            }
        }
    }

    // epilogue: bias + PReLU; write fp32 (final layer) or hi/lo (hidden layers)
    #pragma unroll
    for (int nt = 0; nt < 2; ++nt) {
        int n = w * 32 + nt * 16 + l;
        float b = bl[n], s = slope[n];
        #pragma unroll
        for (int mt = 0; mt < 4; ++mt) {
            #pragma unroll
            for (int rg = 0; rg < 4; ++rg) {
                int r = row0 + mt * 16 + q * 4 + rg;
                if (r < rows) {
                    float v = acc[mt][nt][rg] + b;
                    v = v > 0.f ? v : s * v;
                    if (outf) {
                        outf[(size_t)r * C + n] = v;
                    } else {
                        ushort hh, ll;
                        split_bf16(v, hh, ll);
                        outh[(size_t)r * C + n] = hh;
                        outl[(size_t)r * C + n] = ll;
                    }
                }
            }
        }
    }
}

// ---------------- launch ----------------

extern "C" void kernel_launch(void* const* d_in, const int* in_sizes, int n_in,
                              void* d_out, int out_size, void* d_ws, size_t ws_size,
                              hipStream_t stream) {
    const float* x   = (const float*)d_in[0];
    const int*   src = (const int*)d_in[1];
    const int*   dst = src + NE;
    const float* Wl[3] = {(const float*)d_in[3], (const float*)d_in[7],  (const float*)d_in[11]};
    const float* bl[3] = {(const float*)d_in[4], (const float*)d_in[8],  (const float*)d_in[12]};
    const float* Wr[3] = {(const float*)d_in[5], (const float*)d_in[9],  (const float*)d_in[13]};
    const float* sl[3] = {(const float*)d_in[6], (const float*)d_in[10], (const float*)d_in[14]};

    int*   deg     = (int*)d_ws;             // 50016
    int*   row_ptr = deg + 50016;            // 50016 (uses 50001)
    int*   col     = row_ptr + 50016;        // 800000
    int*   pos     = col + 800000;           // 800000
    float* inv_deg = (float*)(pos + 800000); // 50016
    int*   bsum    = (int*)(inv_deg + 50016);// 256
    int*   boff    = bsum + 256;             // 256
    float* agg     = (float*)(boff + 256);   // NN*C fp32 (16B-aligned)
    ushort* Ah     = (ushort*)(agg + (size_t)NN * C);   // ping hi
    ushort* Al     = Ah + (size_t)NN * C;               // ping lo
    ushort* Bh     = Al + (size_t)NN * C;               // pong hi
    ushort* Bl     = Bh + (size_t)NN * C;               // pong lo

    hipMemsetAsync(deg, 0, 50016 * sizeof(int), stream);

    const int E4B = (NE / 4 + 255) / 256;    // 782 blocks, 4 edges/thread
    count_pos_kernel<<<E4B, 256, 0, stream>>>(dst, deg, pos, NE);
    scan1_kernel<<<SCAN_BLOCKS, 256, 0, stream>>>(deg, row_ptr, inv_deg, bsum, NN);
    scan2_kernel<<<1, 256, 0, stream>>>(bsum, boff, row_ptr, SCAN_BLOCKS, NN);
    scan3_kernel<<<SCAN_BLOCKS, 256, 0, stream>>>(row_ptr, boff, NN);
    fill2_kernel<<<E4B, 256, 0, stream>>>(src, dst, row_ptr, pos, col, NE);

    // split x into ping buffer (hi/lo)
    split_kernel<<<(NN * C / 4 + 255) / 256, 256, 0, stream>>>(x, Ah, Al, NN * C / 4);

    int rows_out = out_size / C;             // 1024

    // layer 0: A -> B
    agg_kernel<<<(NN + 3) / 4, 256, 0, stream>>>(Ah, row_ptr, col, inv_deg, agg, NN);
    gemm_kernel<<<(NN + 63) / 64, 256, 0, stream>>>(agg, Ah, Al, Wl[0], bl[0], Wr[0], sl[0],
                                                    nullptr, Bh, Bl, NN);

    // layer 1: B -> A
    agg_kernel<<<(NN + 3) / 4, 256, 0, stream>>>(Bh, row_ptr, col, inv_deg, agg, NN);
    gemm_kernel<<<(NN + 63) / 64, 256, 0, stream>>>(agg, Bh, Bl, Wl[1], bl[1], Wr[1], sl[1],
                                                    nullptr, Ah, Al, NN);

    // layer 2: A -> d_out (first rows_out nodes only)
    agg_kernel<<<(rows_out + 3) / 4, 256, 0, stream>>>(Ah, row_ptr, col, inv_deg, agg, rows_out);
    gemm_kernel<<<(rows_out + 63) / 64, 256, 0, stream>>>(agg, Ah, Al, Wl[2], bl[2], Wr[2], sl[2],
                                                          (float*)d_out, nullptr, nullptr, rows_out);
}